// Round 2
// baseline (283.585 us; speedup 1.0000x reference)
//
#include <hip/hip_runtime.h>

// EM_fusion: softmax over two identical logits == exactly 0.5, so
// fused = 0.5*(feature_1 + feature_2). Pure memory-bound elementwise op.
// B*D = 131072*768 = 100,663,296 fp32 elements, divisible by 4.
//
// Round 2: unroll x4 (8 independent loads in flight per thread) +
// non-temporal stores (keep the write stream from evicting cached inputs
// in L2/L3 -- round 1 showed L3 serving ~half the read traffic).

typedef float v4f __attribute__((ext_vector_type(4)));

__global__ __launch_bounds__(256) void EM_fusion_avg_kernel(
    const v4f* __restrict__ f1,
    const v4f* __restrict__ f2,
    v4f* __restrict__ out,
    long n4)
{
    const long stride = (long)gridDim.x * blockDim.x;
    long i = (long)blockIdx.x * blockDim.x + threadIdx.x;

    // Main loop: 4 float4s per iteration, independent addresses -> deep MLP.
    for (; i + 3 * stride < n4; i += 4 * stride) {
        v4f a0 = f1[i];
        v4f a1 = f1[i + stride];
        v4f a2 = f1[i + 2 * stride];
        v4f a3 = f1[i + 3 * stride];
        v4f b0 = f2[i];
        v4f b1 = f2[i + stride];
        v4f b2 = f2[i + 2 * stride];
        v4f b3 = f2[i + 3 * stride];
        v4f r0 = 0.5f * (a0 + b0);
        v4f r1 = 0.5f * (a1 + b1);
        v4f r2 = 0.5f * (a2 + b2);
        v4f r3 = 0.5f * (a3 + b3);
        __builtin_nontemporal_store(r0, &out[i]);
        __builtin_nontemporal_store(r1, &out[i + stride]);
        __builtin_nontemporal_store(r2, &out[i + 2 * stride]);
        __builtin_nontemporal_store(r3, &out[i + 3 * stride]);
    }
    // Tail (not taken for the bench shape: 25,165,824 = 48 * 524,288, 48 % 4 == 0)
    for (; i < n4; i += stride) {
        v4f a = f1[i];
        v4f b = f2[i];
        v4f r = 0.5f * (a + b);
        __builtin_nontemporal_store(r, &out[i]);
    }
}

extern "C" void kernel_launch(void* const* d_in, const int* in_sizes, int n_in,
                              void* d_out, int out_size, void* d_ws, size_t ws_size,
                              hipStream_t stream)
{
    const v4f* f1 = (const v4f*)d_in[0];
    const v4f* f2 = (const v4f*)d_in[1];
    v4f* out = (v4f*)d_out;

    const long n = (long)in_sizes[0];   // 100,663,296
    const long n4 = n / 4;              // 25,165,824 (exact)

    const int block = 256;
    const int grid = 2048;              // 256 CU x 8 blocks; 48 float4s/thread

    EM_fusion_avg_kernel<<<grid, block, 0, stream>>>(f1, f2, out, n4);
}

// Round 3
// 233.594 us; speedup vs baseline: 1.2140x; 1.2140x over previous
//
#include <hip/hip_runtime.h>

// EM_fusion: softmax over two identical logits == exactly 0.5, so
// fused = 0.5*(feature_1 + feature_2). Pure memory-bound elementwise op.
// B*D = 131072*768 = 100,663,296 fp32 elements, divisible by 4.
//
// Round 3: round-1 winning structure (simple grid-stride, 245 us, 78% of
// copy ceiling) + ONE change: non-temporal stores. Output is
// write-once-never-read; keeping it out of L2/LLC should preserve more
// LLC capacity for the input read streams (round 1 showed LLC serving
// ~403 MB of the 805 MB logical reads). Round 2 confounded NT stores
// with a x4 unroll; this isolates NT.

typedef float v4f __attribute__((ext_vector_type(4)));

__global__ __launch_bounds__(256) void EM_fusion_avg_kernel(
    const v4f* __restrict__ f1,
    const v4f* __restrict__ f2,
    v4f* __restrict__ out,
    long n4)
{
    long i = (long)blockIdx.x * blockDim.x + threadIdx.x;
    const long stride = (long)gridDim.x * blockDim.x;
    for (; i < n4; i += stride) {
        v4f a = f1[i];
        v4f b = f2[i];
        v4f r = 0.5f * (a + b);
        __builtin_nontemporal_store(r, &out[i]);
    }
}

extern "C" void kernel_launch(void* const* d_in, const int* in_sizes, int n_in,
                              void* d_out, int out_size, void* d_ws, size_t ws_size,
                              hipStream_t stream)
{
    const v4f* f1 = (const v4f*)d_in[0];
    const v4f* f2 = (const v4f*)d_in[1];
    v4f* out = (v4f*)d_out;

    const long n = (long)in_sizes[0];   // 100,663,296
    const long n4 = n / 4;              // 25,165,824 (exact)

    const int block = 256;
    const int grid = 2048;              // 256 CU x 8 blocks, grid-stride covers the rest

    EM_fusion_avg_kernel<<<grid, block, 0, stream>>>(f1, f2, out, n4);
}